// Round 9
// baseline (564.110 us; speedup 1.0000x reference)
//
#include <hip/hip_runtime.h>
#include <stdint.h>

#define NN        150000
#define FF        500
#define XBYTES    300000000u      // NN*FF*4
#define NTHREADS  256
#define NSTEPS    16
#define NBLOCKS   2344            // ceil(150000/64)

// ws layout (bf16): ws0 = W1^T [224 c][512 k] (zero-padded); ws1 = B2^T [64 j][224 k]
#define WS0_ELEMS 114688
#define WS1_ELEMS 14336

// LDS: h1s [64][232] bf16 @0 (29696 B); smalls 944 f32 @29696 (3776 B); zs [64][72] bf16 @33472 (9216 B)
#define SMALLS_OFF 29696
#define ZS_OFF     33472
#define LDS_BYTES  42688

typedef short short8 __attribute__((ext_vector_type(8)));
typedef float float4v __attribute__((ext_vector_type(4)));

__device__ __forceinline__ short f2bf(float f) {
    uint32_t u = __float_as_uint(f);
    u = (u + 0x7FFFu + ((u >> 16) & 1u)) >> 16;   // RNE
    return (short)u;
}
__device__ __forceinline__ float bf2f(short s) {
    return __uint_as_float(((uint32_t)(uint16_t)s) << 16);
}
__device__ __forceinline__ short8 cvt8(float4v lo, float4v hi) {
    int r0, r1, r2, r3;
    asm("v_cvt_pk_bf16_f32 %0, %1, %2" : "=v"(r0) : "v"(lo[0]), "v"(lo[1]));
    asm("v_cvt_pk_bf16_f32 %0, %1, %2" : "=v"(r1) : "v"(lo[2]), "v"(lo[3]));
    asm("v_cvt_pk_bf16_f32 %0, %1, %2" : "=v"(r2) : "v"(hi[0]), "v"(hi[1]));
    asm("v_cvt_pk_bf16_f32 %0, %1, %2" : "=v"(r3) : "v"(hi[2]), "v"(hi[3]));
    union { int i[4]; short8 s; } u;
    u.i[0] = r0; u.i[1] = r1; u.i[2] = r2; u.i[3] = r3;
    return u.s;
}

// ---------------- prep: plain [c][k] bf16 W1^T and masked B2^T ----------------
__global__ __launch_bounds__(256) void prep_kernel(
    const float* __restrict__ W1, const float* __restrict__ W2,
    const float* __restrict__ mask1, short* __restrict__ ws)
{
    int idx = blockIdx.x * 256 + threadIdx.x;
    if (idx < WS0_ELEMS) {
        int c = idx >> 9, k = idx & 511;
        float v = (c < 200 && k < 500) ? W1[k * 200 + c] : 0.f;
        ws[idx] = f2bf(v);
    } else if (idx < WS0_ELEMS + WS1_ELEMS) {
        int r = idx - WS0_ELEMS;
        int j = r / 224;
        int k = r - j * 224;
        int m = j >> 3, c = j & 7;
        float v = 0.f;
        if (k < 200 && mask1[m * 200 + k] > 0.f) v = W2[k * 8 + c];
        ws[idx] = f2bf(v);
    }
}

// ---------------- fused: barrier-free K-loop, all-register streaming ----------------
__global__ __launch_bounds__(NTHREADS, 3) void fused_kernel(
    const float* __restrict__ x,  const float* __restrict__ b1,
    const float* __restrict__ b2, const float* __restrict__ mask2,
    const float* __restrict__ hw1, const float* __restrict__ hb1,
    const float* __restrict__ hw2, const float* __restrict__ hb2,
    const short* __restrict__ ws, float* __restrict__ out)
{
    __shared__ __align__(16) char lds[LDS_BYTES];

    const int tid  = threadIdx.x;
    const int lane = tid & 63;
    const int w    = tid >> 6;       // 0..3
    const int l15  = lane & 15;
    const int l4   = lane >> 4;
    const int n0   = blockIdx.x * 64;
    const int wrow = w >> 1;         // 0..1 (32-row groups)
    const int wcol = w & 1;          // 0..1 (112-col groups)

    const char* xb  = (const char*)x;
    const char* wsb = (const char*)ws;

    // ---- per-lane A byte-bases (row from l15, k-chunk from l4) ----
    uint32_t abase[2];
    #pragma unroll
    for (int i = 0; i < 2; ++i) {
        int row = n0 + wrow * 32 + i * 16 + l15;
        if (row > NN - 1) row = NN - 1;
        abase[i] = (uint32_t)row * 2000u + (uint32_t)l4 * 32u;
    }
    // ---- per-lane B pointers (col from l15, k-chunk from l4) ----
    const char* bp[7];
    #pragma unroll
    for (int j = 0; j < 7; ++j) {
        int col = wcol * 112 + j * 16 + l15;
        bp[j] = wsb + (uint32_t)col * 1024u + (uint32_t)l4 * 16u;
    }

    float4v acc[2][7];
    #pragma unroll
    for (int i = 0; i < 2; ++i)
        #pragma unroll
        for (int j = 0; j < 7; ++j) acc[i][j] = (float4v)0.f;

    float4v alo[2][2], ahi[2][2];   // [slot][frag]
    short8  bs[7];

    auto lda = [&](int slot, int t) {
        #pragma unroll
        for (int i = 0; i < 2; ++i) {
            uint32_t a0 = abase[i] + (uint32_t)(t * 128);
            uint32_t a1 = a0 + 16u;
            if (a0 > XBYTES - 16u) a0 = XBYTES - 16u;   // clamp: only k>=500 slots (zero W1) affected
            if (a1 > XBYTES - 16u) a1 = XBYTES - 16u;
            alo[slot][i] = *(const float4v*)(xb + a0);
            ahi[slot][i] = *(const float4v*)(xb + a1);
        }
    };
    auto ldb = [&](int t) {
        #pragma unroll
        for (int j = 0; j < 7; ++j)
            bs[j] = *(const short8*)(bp[j] + t * 64);
    };

    // ---- GEMM1 K-loop: no LDS, no barriers; 2-slot A rotation, 1-slot B ----
    lda(0, 0);
    lda(1, 1);
    ldb(0);
    #pragma unroll
    for (int t = 0; t < NSTEPS; ++t) {
        const int slot = t & 1;
        short8 a0 = cvt8(alo[slot][0], ahi[slot][0]);
        short8 a1 = cvt8(alo[slot][1], ahi[slot][1]);
        #pragma unroll
        for (int j = 0; j < 7; ++j) {
            short8 b = bs[j];
            acc[0][j] = __builtin_amdgcn_mfma_f32_16x16x32_bf16(a0, b, acc[0][j], 0, 0, 0);
            acc[1][j] = __builtin_amdgcn_mfma_f32_16x16x32_bf16(a1, b, acc[1][j], 0, 0, 0);
        }
        if (t + 1 < NSTEPS) ldb(t + 1);
        if (t + 2 < NSTEPS) lda(slot, t + 2);
    }

    // ---- stage small params ----
    float* smalls = (float*)(lds + SMALLS_OFF);
    for (int i = tid; i < 944; i += NTHREADS) {
        float v;
        if      (i < 224) v = (i < 200) ? b1[i] : 0.f;            // b1s @0
        else if (i < 232) v = b2[i - 224];                        // b2s @224
        else if (i < 296) v = (mask2[i - 232] > 0.f) ? 1.f : 0.f; // m2s @232
        else if (i < 808) v = hw1[i - 296];                       // hw1s @296
        else if (i < 872) v = hb1[i - 808];                       // hb1s @808
        else if (i < 936) v = hw2[i - 872];                       // hw2s @872
        else              v = hb2[i - 936];                       // hb2s @936
        smalls[i] = v;
    }
    __syncthreads();

    // ---- GEMM1 epilogue: bias + relu -> h1s [64][232] bf16 ----
    #pragma unroll
    for (int j = 0; j < 7; ++j) {
        int col = wcol * 112 + j * 16 + l15;
        float bb = smalls[col];
        #pragma unroll
        for (int i = 0; i < 2; ++i) {
            int rowb = wrow * 32 + i * 16 + l4 * 4;
            #pragma unroll
            for (int r = 0; r < 4; ++r) {
                float v = acc[i][j][r] + bb;
                v = v > 0.f ? v : 0.f;
                *(short*)(lds + (rowb + r) * 464 + col * 2) = f2bf(v);
            }
        }
    }
    __syncthreads();

    // ---- GEMM2: h2[64][64] = h1s[64][224] @ B2[224][64]; wave w owns rows w*16..+16 ----
    float4v acc2[4];
    #pragma unroll
    for (int jf = 0; jf < 4; ++jf) acc2[jf] = (float4v)0.f;

    const char* wb2 = wsb + (uint32_t)WS0_ELEMS * 2u;
    const char* b2p[4];
    #pragma unroll
    for (int jf = 0; jf < 4; ++jf)
        b2p[jf] = wb2 + (uint32_t)(jf * 16 + l15) * 448u + (uint32_t)l4 * 16u;

    const char* h1base = lds + (w * 16 + l15) * 464 + l4 * 16;

    short8 b2c[4];
    #pragma unroll
    for (int jf = 0; jf < 4; ++jf) b2c[jf] = *(const short8*)(b2p[jf]);
    #pragma unroll
    for (int s = 0; s < 7; ++s) {
        short8 a2 = *(const short8*)(h1base + s * 64);
        short8 b2n[4];
        if (s < 6) {
            #pragma unroll
            for (int jf = 0; jf < 4; ++jf) b2n[jf] = *(const short8*)(b2p[jf] + (s + 1) * 64);
        }
        #pragma unroll
        for (int jf = 0; jf < 4; ++jf)
            acc2[jf] = __builtin_amdgcn_mfma_f32_16x16x32_bf16(a2, b2c[jf], acc2[jf], 0, 0, 0);
        if (s < 6) {
            #pragma unroll
            for (int jf = 0; jf < 4; ++jf) b2c[jf] = b2n[jf];
        }
    }

    // ---- GEMM2 epilogue: z = (h2 + b2) * m2 -> zs [64][72] bf16 ----
    short* zs = (short*)(lds + ZS_OFF);
    #pragma unroll
    for (int jf = 0; jf < 4; ++jf) {
        int j = jf * 16 + l15;
        float bias  = smalls[224 + (j & 7)];
        float scale = smalls[232 + j];
        int rowb = w * 16 + l4 * 4;
        #pragma unroll
        for (int r = 0; r < 4; ++r) {
            float z = (acc2[jf][r] + bias) * scale;
            zs[(rowb + r) * 72 + j] = f2bf(z);
        }
    }
    __syncthreads();

    // ---- head: per (node, module-pair) tiny MLP + sigmoid ----
    {
        int n  = tid >> 2;          // 0..63
        int m0 = (tid & 3) * 2;     // 0,2,4,6
        short8 za = *(const short8*)(zs + n * 72 + m0 * 8);
        short8 zb = *(const short8*)(zs + n * 72 + m0 * 8 + 8);
        float o[2];
        #pragma unroll
        for (int mm = 0; mm < 2; ++mm) {
            int m = m0 + mm;
            float hid[8];
            #pragma unroll
            for (int h = 0; h < 8; ++h) hid[h] = smalls[808 + m * 8 + h];
            #pragma unroll
            for (int c = 0; c < 8; ++c) {
                float zc = bf2f(mm == 0 ? za[c] : zb[c]);
                const float* wv = smalls + 296 + (m * 8 + c) * 8;
                #pragma unroll
                for (int h = 0; h < 8; ++h) hid[h] += zc * wv[h];
            }
            float u = smalls[936 + m];
            #pragma unroll
            for (int h = 0; h < 8; ++h) {
                float hv = hid[h] > 0.f ? hid[h] : 0.f;
                u += hv * smalls[872 + m * 8 + h];
            }
            o[mm] = 1.f / (1.f + __expf(-u));
        }
        int gn = n0 + n;
        if (gn < NN) {
            float2 ov = make_float2(o[0], o[1]);
            *(float2*)(out + (long)gn * 8 + m0) = ov;
        }
    }
}

extern "C" void kernel_launch(void* const* d_in, const int* in_sizes, int n_in,
                              void* d_out, int out_size, void* d_ws, size_t ws_size,
                              hipStream_t stream)
{
    const float* x     = (const float*)d_in[0];
    const float* W1    = (const float*)d_in[1];
    const float* b1    = (const float*)d_in[2];
    const float* W2    = (const float*)d_in[3];
    const float* b2    = (const float*)d_in[4];
    const float* mask1 = (const float*)d_in[5];
    const float* mask2 = (const float*)d_in[6];
    const float* hw1   = (const float*)d_in[7];
    const float* hb1   = (const float*)d_in[8];
    const float* hw2   = (const float*)d_in[9];
    const float* hb2   = (const float*)d_in[10];
    short* ws  = (short*)d_ws;
    float* out = (float*)d_out;

    if (ws_size < (size_t)(WS0_ELEMS + WS1_ELEMS) * sizeof(short)) return;

    int prep_blocks = (WS0_ELEMS + WS1_ELEMS + 255) / 256;   // 504
    prep_kernel<<<prep_blocks, 256, 0, stream>>>(W1, W2, mask1, ws);

    fused_kernel<<<NBLOCKS, NTHREADS, 0, stream>>>(
        x, b1, b2, mask2, hw1, hb1, hw2, hb2, ws, out);
}